// Round 2
// baseline (250.051 us; speedup 1.0000x reference)
//
#include <hip/hip_runtime.h>
#include <math.h>

// ws layout (float offsets) — total footprint 154,464 floats (617,856 B),
// strictly inside the previously-proven 154,624-float workspace.
// The hop "ping" buffer lives in d_out (768 floats, dead until k_tail).
#define WS_KV 0        // 300: Wk @ u                      (16B aligned)
#define WS_C0 300      // bk . u
#define WS_C1 301      // bq . u2
#define WS_H1 304      // 300: hop pong (final g after 3 hops)
#define WS_DEN 604     // 256: per-row softmax denom (atomic)
#define WS_MW 864      // 256*300: unnormalized sum p*w*emb (atomic, 16B aligned)
#define WS_VS 77664    // 256*300: v_s, pre-divided by mem_len (atomic, 16B aligned)
#define WS_END 154464

__device__ __forceinline__ float wred(float v) {
#pragma unroll
    for (int off = 32; off > 0; off >>= 1) v += __shfl_xor(v, off);
    return v;
}

// ---------------------------------------------------------------------------
// k_prep: grid 302 x 64. One wave per output — all loads issue in one round.
//  blocks 0..299: kv[j] = dot(Wk row j, u); h0[j] = dot(Wq row j, u2)
//  block 300: c0 = bk.u ; block 301: c1 = bq.u2
//  h0 = d_out used as scratch (hop ping buffer).
//  ALL blocks additionally zero the atomic-accumulator region [WS_DEN, WS_END).
// ---------------------------------------------------------------------------
__global__ __launch_bounds__(64) void k_prep(
    const float* __restrict__ Wk, const float* __restrict__ bk,
    const float* __restrict__ Wq, const float* __restrict__ bq,
    const float* __restrict__ wmlp, float* __restrict__ h0,
    float* __restrict__ ws)
{
    const int lane = threadIdx.x;
    const int j = blockIdx.x;
    const float* u  = wmlp;
    const float* u2 = wmlp + 300;
    if (j < 300) {
        float pk = 0.f, pq = 0.f;
#pragma unroll
        for (int k = 0; k < 5; ++k) {
            int idx = lane + 64 * k;
            if (idx < 300) {
                pk += Wk[j * 300 + idx] * u[idx];
                pq += Wq[j * 300 + idx] * u2[idx];
            }
        }
        pk = wred(pk); pq = wred(pq);
        if (lane == 0) { ws[WS_KV + j] = pk; h0[j] = pq; }
    } else if (j == 300) {
        float p = 0.f;
#pragma unroll
        for (int k = 0; k < 5; ++k) { int idx = lane + 64 * k; if (idx < 300) p += bk[idx] * u[idx]; }
        p = wred(p);
        if (lane == 0) ws[WS_C0] = p;
    } else {
        float p = 0.f;
#pragma unroll
        for (int k = 0; k < 5; ++k) { int idx = lane + 64 * k; if (idx < 300) p += bq[idx] * u2[idx]; }
        p = wred(p);
        if (lane == 0) ws[WS_C1] = p;
    }
    // zero the atomic accumulators (runs before k_main in stream order)
    const int zb = WS_DEN + j * 512 + lane * 8;
#pragma unroll
    for (int k = 0; k < 2; ++k) {
        int o = zb + 4 * k;
        if (o < WS_END) *(float4*)(ws + o) = make_float4(0.f, 0.f, 0.f, 0.f);
    }
}

// ---------------------------------------------------------------------------
// k_hop: grid 300 x 64: dst[j] = dot(Wx row j, src). Launched 3x (ping-pong
// between d_out scratch and ws+WS_H1; final g lands in ws+WS_H1).
// ---------------------------------------------------------------------------
__global__ __launch_bounds__(64) void k_hop(
    const float* __restrict__ Wx, const float* __restrict__ src,
    float* __restrict__ dst)
{
    const int lane = threadIdx.x;
    const int j = blockIdx.x;
    float p = 0.f;
#pragma unroll
    for (int k = 0; k < 5; ++k) {
        int idx = lane + 64 * k;
        if (idx < 300) p += Wx[j * 300 + idx] * src[idx];
    }
    p = wred(p);
    if (lane == 0) dst[j] = p;
}

// ---------------------------------------------------------------------------
// k_main: grid 1024 x 512. FOUR blocks per batch row (128 tokens each);
// 8 waves x 16 tokens. float4 row loads, ILP-2 token pairs, fast exp(tanh),
// cross-block combine via device-scope fp32 atomics into ws.
// ---------------------------------------------------------------------------
__global__ __launch_bounds__(512, 6) void k_main(
    const int* __restrict__ text, const int* __restrict__ aspect,
    const int* __restrict__ left, const float* __restrict__ embed,
    float* __restrict__ ws)
{
    const int b = blockIdx.x >> 2;
    const int chunk = blockIdx.x & 3;
    const int t = threadIdx.x;
    const int wv = t >> 6;
    const int lane = t & 63;
    const int lbase = chunk * 128;

    __shared__ int   toks[128];
    __shared__ int   atoks[8];
    __shared__ float red[8];
    __shared__ __align__(16) float accW[8 * 300];
    __shared__ __align__(16) float vsW[8 * 300];
    __shared__ float denomW[8];
    __shared__ int   cnts[3];
    __shared__ float sc[4];

    if (t < 3) cnts[t] = 0;
    __syncthreads();

    // full-row counts (all 512 tokens), plus stash this block's 128 tokens
    int tk = text[b * 512 + t];
    bool predm = (tk != 0);
    bool predl = false, preda = false;
    if ((unsigned)(t - lbase) < 128u) toks[t - lbase] = tk;
    if (t < 64) predl = (left[b * 64 + t] != 0);
    if (t < 8) { int ak = aspect[b * 8 + t]; atoks[t] = ak; preda = (ak != 0); }
    {
        unsigned long long m;
        m = __ballot(predm); if (lane == 0 && m) atomicAdd(&cnts[0], __popcll(m));
        m = __ballot(predl); if (lane == 0 && m) atomicAdd(&cnts[1], __popcll(m));
        m = __ballot(preda); if (lane == 0 && m) atomicAdd(&cnts[2], __popcll(m));
    }
    __syncthreads();

    // qb = asp_e . g  (wave-partial shuffle reduce)
    float prod = 0.f;
    if (t < 300) {
        float s = 0.f;
#pragma unroll
        for (int a = 0; a < 8; ++a) s += embed[(size_t)atoks[a] * 300 + t];
        prod = (s / (float)cnts[2]) * ws[WS_H1 + t];
    }
    prod = wred(prod);
    if (lane == 0) red[wv] = prod;
    __syncthreads();
    if (t == 0) {
        sc[0] = (float)cnts[0];
        sc[1] = (float)(cnts[1] - cnts[2]);
        sc[2] = (float)cnts[1];
        float q = 0.f;
#pragma unroll
        for (int w = 0; w < 8; ++w) q += red[w];
        sc[3] = q + ws[WS_C0] + ws[WS_C1];
    }
    __syncthreads();
    const float mem_len_f = sc[0], startf = sc[1], endf = sc[2], qb = sc[3];

    const float4* kv4 = (const float4*)(ws + WS_KV);
    const float4* emb4 = (const float4*)embed;   // row = tok*75 float4s
    const bool hasB = (lane < 11);
    const float4 kva = kv4[lane];
    const float4 kvb = hasB ? kv4[64 + lane] : make_float4(0.f, 0.f, 0.f, 0.f);

    float4 accA = make_float4(0.f,0.f,0.f,0.f), accB = make_float4(0.f,0.f,0.f,0.f);
    float4 vsA  = make_float4(0.f,0.f,0.f,0.f), vsB  = make_float4(0.f,0.f,0.f,0.f);
    float denom = 0.f;

    for (int it = 0; it < 8; ++it) {
        const int lt = wv * 16 + 2 * it;
        const int l0 = lbase + lt, l1 = l0 + 1;
        const long r0 = (long)toks[lt] * 75, r1 = (long)toks[lt + 1] * 75;
        float4 a0 = emb4[r0 + lane];
        float4 a1 = emb4[r1 + lane];
        float4 b0 = hasB ? emb4[r0 + 64 + lane] : make_float4(0.f,0.f,0.f,0.f);
        float4 b1 = hasB ? emb4[r1 + 64 + lane] : make_float4(0.f,0.f,0.f,0.f);

        float pd0 = a0.x*kva.x + a0.y*kva.y + a0.z*kva.z + a0.w*kva.w
                  + b0.x*kvb.x + b0.y*kvb.y + b0.z*kvb.z + b0.w*kvb.w;
        float pd1 = a1.x*kva.x + a1.y*kva.y + a1.z*kva.z + a1.w*kva.w
                  + b1.x*kvb.x + b1.y*kvb.y + b1.z*kvb.z + b1.w*kvb.w;
#pragma unroll
        for (int off = 32; off > 0; off >>= 1) {
            pd0 += __shfl_xor(pd0, off);
            pd1 += __shfl_xor(pd1, off);
        }

        const float f0 = (float)l0, f1 = (float)l1;
        float lv0 = (f0 < startf) ? (startf - f0) : ((f0 <= endf) ? 0.f : (f0 - endf));
        float lv1 = (f1 < startf) ? (startf - f1) : ((f1 <= endf) ? 0.f : (f1 - endf));
        float w0 = 1.f - lv0 / mem_len_f; w0 = (f0 < mem_len_f) ? w0 : 0.f;
        float w1 = 1.f - lv1 / mem_len_f; w1 = (f1 < mem_len_f) ? w1 : 0.f;

        // p = exp(tanh(s)) via tanh(s) = (e^{2s}-1)/(e^{2s}+1); clamp keeps e^{2s} finite
        float s0 = w0 * pd0 + qb; s0 = fminf(fmaxf(s0, -15.f), 15.f);
        float s1 = w1 * pd1 + qb; s1 = fminf(fmaxf(s1, -15.f), 15.f);
        float e0 = __expf(2.f * s0);
        float e1 = __expf(2.f * s1);
        const float p0 = __expf((e0 - 1.f) / (e0 + 1.f));
        const float p1 = __expf((e1 - 1.f) / (e1 + 1.f));
        const float pw0 = p0 * w0, pw1 = p1 * w1;

        accA.x += pw0*a0.x + pw1*a1.x;  accA.y += pw0*a0.y + pw1*a1.y;
        accA.z += pw0*a0.z + pw1*a1.z;  accA.w += pw0*a0.w + pw1*a1.w;
        accB.x += pw0*b0.x + pw1*b1.x;  accB.y += pw0*b0.y + pw1*b1.y;
        accB.z += pw0*b0.z + pw1*b1.z;  accB.w += pw0*b0.w + pw1*b1.w;
        vsA.x += a0.x + a1.x;  vsA.y += a0.y + a1.y;
        vsA.z += a0.z + a1.z;  vsA.w += a0.w + a1.w;
        vsB.x += b0.x + b1.x;  vsB.y += b0.y + b1.y;
        vsB.z += b0.z + b1.z;  vsB.w += b0.w + b1.w;
        denom += p0 + p1;
    }

    *(float4*)&accW[wv * 300 + 4 * lane] = accA;
    *(float4*)&vsW [wv * 300 + 4 * lane] = vsA;
    if (hasB) {
        *(float4*)&accW[wv * 300 + 256 + 4 * lane] = accB;
        *(float4*)&vsW [wv * 300 + 256 + 4 * lane] = vsB;
    }
    if (lane == 0) denomW[wv] = denom;
    __syncthreads();

    if (t < 300) {
        float ds = 0.f;
#pragma unroll
        for (int w = 0; w < 8; ++w) ds += denomW[w];
        float ms = 0.f, vs = 0.f;
#pragma unroll
        for (int w = 0; w < 8; ++w) { ms += accW[w * 300 + t]; vs += vsW[w * 300 + t]; }
        atomicAdd(&ws[WS_MW + b * 300 + t], ms);
        atomicAdd(&ws[WS_VS + b * 300 + t], vs / mem_len_f);
        if (t == 0) atomicAdd(&ws[WS_DEN + b], ds);
    }
}

// ---------------------------------------------------------------------------
// k_tail: grid 256 x 960. One batch row per block; 3-way K-split per GEMM.
// mw = MW/denom ; t1 = mw@Wk + bk ; vns = t1@Wproj + bproj + v_s ;
// vms = tanh(vns@Wm + bm) ; out = softmax(vms@Wd + bd)
// ---------------------------------------------------------------------------
__global__ __launch_bounds__(960) void k_tail(
    const float* __restrict__ Wk, const float* __restrict__ bk,
    const float* __restrict__ Wproj, const float* __restrict__ bproj,
    const float* __restrict__ Wm, const float* __restrict__ bm,
    const float* __restrict__ Wd, const float* __restrict__ bd,
    float* __restrict__ out, const float* __restrict__ ws)
{
    const int t = threadIdx.x;
    const int b = blockIdx.x;
    const int seg = t / 320;      // 0..2 (K-split)
    const int j = t - seg * 320;  // 0..319 (output col)

    __shared__ float A[300], T[300], part[900], vms[300], lg[3];

    if (t < 300) A[t] = ws[WS_MW + b * 300 + t] / ws[WS_DEN + b];
    __syncthreads();

    // GEMM1: T = A @ Wk + bk
    if (j < 300) {
        const int k0 = seg * 100;
        float acc = 0.f;
#pragma unroll 10
        for (int i = 0; i < 100; ++i) acc += A[k0 + i] * Wk[(k0 + i) * 300 + j];
        part[seg * 300 + j] = acc;
    }
    __syncthreads();
    if (t < 300) T[t] = part[t] + part[300 + t] + part[600 + t] + bk[t];
    __syncthreads();

    // GEMM2: A = T @ Wproj + bproj + v_s
    if (j < 300) {
        const int k0 = seg * 100;
        float acc = 0.f;
#pragma unroll 10
        for (int i = 0; i < 100; ++i) acc += T[k0 + i] * Wproj[(k0 + i) * 300 + j];
        part[seg * 300 + j] = acc;
    }
    __syncthreads();
    if (t < 300) A[t] = part[t] + part[300 + t] + part[600 + t] + bproj[t] + ws[WS_VS + b * 300 + t];
    __syncthreads();

    // GEMM3: vms = tanh(A @ Wm + bm)
    if (j < 300) {
        const int k0 = seg * 100;
        float acc = 0.f;
#pragma unroll 10
        for (int i = 0; i < 100; ++i) acc += A[k0 + i] * Wm[(k0 + i) * 300 + j];
        part[seg * 300 + j] = acc;
    }
    __syncthreads();
    if (t < 300) vms[t] = tanhf(part[t] + part[300 + t] + part[600 + t] + bm[t]);
    __syncthreads();

    // logits: waves 0..2 each handle one class p
    const int wv = t >> 6, lane = t & 63;
    if (wv < 3) {
        float p = 0.f;
#pragma unroll
        for (int k = 0; k < 5; ++k) { int d = lane + 64 * k; if (d < 300) p += vms[d] * Wd[d * 3 + wv]; }
        p = wred(p);
        if (lane == 0) lg[wv] = p + bd[wv];
    }
    __syncthreads();
    if (t == 0) {
        float l0 = lg[0], l1 = lg[1], l2 = lg[2];
        float mx = fmaxf(l0, fmaxf(l1, l2));
        float e0 = expf(l0 - mx), e1 = expf(l1 - mx), e2 = expf(l2 - mx);
        float s = e0 + e1 + e2;
        out[b * 3 + 0] = e0 / s;
        out[b * 3 + 1] = e1 / s;
        out[b * 3 + 2] = e2 / s;
    }
}

extern "C" void kernel_launch(void* const* d_in, const int* in_sizes, int n_in,
                              void* d_out, int out_size, void* d_ws, size_t ws_size,
                              hipStream_t stream)
{
    (void)in_sizes; (void)n_in; (void)out_size; (void)ws_size;
    const int*   text   = (const int*)d_in[0];
    const int*   aspect = (const int*)d_in[1];
    const int*   left   = (const int*)d_in[2];
    const float* embed  = (const float*)d_in[3];
    const float* Wx     = (const float*)d_in[4];
    // d_in[5] = Ws : dead code in reference
    const float* Wk     = (const float*)d_in[6];
    const float* bk     = (const float*)d_in[7];
    const float* Wq     = (const float*)d_in[8];
    const float* bq     = (const float*)d_in[9];
    const float* wmlp   = (const float*)d_in[10];
    const float* Wproj  = (const float*)d_in[11];
    const float* bproj  = (const float*)d_in[12];
    const float* Wm     = (const float*)d_in[13];
    const float* bm     = (const float*)d_in[14];
    const float* Wd     = (const float*)d_in[15];
    const float* bd     = (const float*)d_in[16];
    float* out = (float*)d_out;
    float* ws  = (float*)d_ws;

    // d_out doubles as the hop ping buffer until k_tail overwrites it.
    hipLaunchKernelGGL(k_prep, dim3(302), dim3(64), 0, stream, Wk, bk, Wq, bq, wmlp, out, ws);
    hipLaunchKernelGGL(k_hop, dim3(300), dim3(64), 0, stream, Wx, out, ws + WS_H1);
    hipLaunchKernelGGL(k_hop, dim3(300), dim3(64), 0, stream, Wx, ws + WS_H1, out);
    hipLaunchKernelGGL(k_hop, dim3(300), dim3(64), 0, stream, Wx, out, ws + WS_H1);
    hipLaunchKernelGGL(k_main, dim3(1024), dim3(512), 0, stream, text, aspect, left, embed, ws);
    hipLaunchKernelGGL(k_tail, dim3(256), dim3(960), 0, stream,
                       Wk, bk, Wproj, bproj, Wm, bm, Wd, bd, out, ws);
}